// Round 2
// 1398.984 us; speedup vs baseline: 1.2855x; 1.2855x over previous
//
#include <hip/hip_runtime.h>

#define MROWS 100352   // 2048*49
#define CIN   1024
#define DIMV  512
#define NTOK  49
#define NH    8
#define HD    64
#define NWIN  256

typedef float f32x4 __attribute__((ext_vector_type(4)));
typedef __bf16 bf16x8 __attribute__((ext_vector_type(8)));
typedef unsigned short u16;
typedef unsigned short u16x8 __attribute__((ext_vector_type(8)));
typedef unsigned int u32;

__device__ __forceinline__ u16 f2bf(float f) {
  u32 b = __builtin_bit_cast(u32, f);
  b += 0x7FFFu + ((b >> 16) & 1u);
  return (u16)(b >> 16);
}
__device__ __forceinline__ float bf2f(u16 u) {
  u32 b = ((u32)u) << 16;
  return __builtin_bit_cast(float, b);
}

// async global->LDS, 16B per lane. LDS dest must be wave-uniform base + lane*16.
__device__ __forceinline__ void async_copy16(u16* lds, const u16* g) {
  __builtin_amdgcn_global_load_lds(
      (__attribute__((address_space(1))) const u32*)(const void*)g,
      (__attribute__((address_space(3))) u32*)(void*)lds, 16, 0, 0);
}

// ---------------- elementwise f32 -> bf16 ----------------
__global__ __launch_bounds__(256) void convert_f32_bf16_kernel(
    const float4* __restrict__ in, ushort4* __restrict__ out, long n4) {
  long i = (long)blockIdx.x * 256 + threadIdx.x;
  if (i < n4) {
    float4 v = in[i];
    ushort4 o;
    o.x = f2bf(v.x); o.y = f2bf(v.y); o.z = f2bf(v.z); o.w = f2bf(v.w);
    out[i] = o;
  }
}

// ---------------- tiled transpose: in (rows x cols f32) -> out[c*ldo + r] bf16 ----------------
__global__ __launch_bounds__(256) void transpose_f32_bf16_kernel(
    const float* __restrict__ in, int rows, int cols, u16* __restrict__ out, int ldo) {
  __shared__ float tile[32][33];
  const int tx = threadIdx.x & 31;
  const int ty = threadIdx.x >> 5;   // 0..7
  const int c0 = blockIdx.x * 32;
  const int r0 = blockIdx.y * 32;
#pragma unroll
  for (int rr = 0; rr < 4; rr++) {
    int r = ty + rr * 8;
    tile[r][tx] = in[(size_t)(r0 + r) * cols + c0 + tx];
  }
  __syncthreads();
#pragma unroll
  for (int rr = 0; rr < 4; rr++) {
    int n = ty + rr * 8;  // column in tile -> output row
    out[(size_t)(c0 + n) * ldo + r0 + tx] = f2bf(tile[tx][n]);
  }
}

__global__ void bias_concat_kernel(const float* __restrict__ bq,
                                   const float* __restrict__ bk,
                                   float* __restrict__ bqk) {
  int i = blockIdx.x * 256 + threadIdx.x;
  if (i < 512) bqk[i] = bq[i];
  else if (i < 1024) bqk[i] = bk[i - 512];
}

// ---------------- bf16 GEMM: C(MxN) = A(MxK, stride lda) @ BT(NxK)^T + bias ----------------
// 128x128 tile, 4 waves, each 4x4 of 16x16x32 MFMA. BK=32.
template <int OUT_BF16>
__global__ __launch_bounds__(256) void gemm_bt_kernel(
    const u16* __restrict__ A, int lda, const u16* __restrict__ BT,
    const float* __restrict__ bias, void* __restrict__ Cv, int ldc, int K) {
  __shared__ u16 lA[128 * 32];
  __shared__ u16 lB[128 * 32];
  const int tid = threadIdx.x;
  const int bn = blockIdx.x, bm = blockIdx.y;
  const int wave = tid >> 6, lane = tid & 63;
  const int wm = (wave & 1) * 64, wn = (wave >> 1) * 64;
  const int fm = lane & 15;
  const int fk = (lane >> 4) * 8;

  const int srow = tid >> 2;        // 0..63
  const int skoff = (tid & 3) * 8;  // 0,8,16,24
  const u16* Ab = A + (size_t)(bm * 128 + srow) * lda + skoff;
  const u16* Bb = BT + (size_t)(bn * 128 + srow) * K + skoff;
  u16* lAp = &lA[srow * 32 + skoff];
  u16* lBp = &lB[srow * 32 + skoff];
  const size_t a64 = (size_t)64 * lda;
  const size_t b64 = (size_t)64 * K;

  f32x4 acc[4][4] = {};

  for (int kt = 0; kt < K; kt += 32) {
    __syncthreads();
    async_copy16(lAp, Ab + kt);
    async_copy16(lAp + 64 * 32, Ab + kt + a64);
    async_copy16(lBp, Bb + kt);
    async_copy16(lBp + 64 * 32, Bb + kt + b64);
    __syncthreads();  // compiler emits vmcnt(0) drain before barrier
    bf16x8 af[4], bfr[4];
#pragma unroll
    for (int i = 0; i < 4; i++)
      af[i] = *(const bf16x8*)&lA[(wm + i * 16 + fm) * 32 + fk];
#pragma unroll
    for (int j = 0; j < 4; j++)
      bfr[j] = *(const bf16x8*)&lB[(wn + j * 16 + fm) * 32 + fk];
#pragma unroll
    for (int i = 0; i < 4; i++)
#pragma unroll
      for (int j = 0; j < 4; j++)
        acc[i][j] = __builtin_amdgcn_mfma_f32_16x16x32_bf16(af[i], bfr[j], acc[i][j], 0, 0, 0);
  }

  // C/D layout: col = lane&15 (N), row = (lane>>4)*4 + reg (M)
  const int row0 = bm * 128 + wm + (lane >> 4) * 4;
  const int col0 = bn * 128 + wn + fm;
#pragma unroll
  for (int j = 0; j < 4; j++) {
    const int col = col0 + j * 16;
    const float bb = bias[col];
#pragma unroll
    for (int i = 0; i < 4; i++) {
#pragma unroll
      for (int r = 0; r < 4; r++) {
        const int row = row0 + i * 16 + r;
        float v = acc[i][j][r] + bb;
        if (OUT_BF16)
          ((u16*)Cv)[(size_t)row * ldc + col] = f2bf(v);
        else
          ((float*)Cv)[(size_t)row * ldc + col] = v;
      }
    }
  }
}

// ---------------- per-(window,head) MFMA attention ----------------
// QK: M x 1024 bf16 (cols 0..511 = Q, 512..1023 = K); V: M x 512 bf16
// Att: M x 512 bf16.
// Grid: 2 blocks per window (4096 total), 4 waves/block, 1 wave = 1 head.
// N=49 padded to 64. S = Q@K^T via 16x16x32 MFMA (A=Q rows, B=K rows — both
// contiguous 16B/lane loads, same lane mapping as the verified gemm_bt_kernel).
// Softmax: wave-parallel, per-row = in-reg max over n-tiles + 4 shfl_xor.
// P staged bf16 in wave-private LDS with XOR swizzle (G4) for b128 A-frag reads.
__global__ __launch_bounds__(256) void attn_kernel(
    const u16* __restrict__ QK, const u16* __restrict__ V,
    const float* __restrict__ mask, u16* __restrict__ Att) {
  __shared__ float msk[NTOK * NTOK];   // 9604 B, shared by the 4 heads
  __shared__ u16 Pl[4][64 * 64];       // 8 KB per wave, XOR-swizzled rows
  const int tid = threadIdx.x;
  const int wv = tid >> 6, lane = tid & 63;
  const int b = blockIdx.x >> 1;
  const int h = ((blockIdx.x & 1) << 2) | wv;
  const size_t rowbase = (size_t)b * NTOK;

  const float* mwin = mask + (size_t)(b & (NWIN - 1)) * (NTOK * NTOK);
  for (int e = tid; e < NTOK * NTOK; e += 256) msk[e] = mwin[e];
  __syncthreads();

  const int fr = lane & 15;       // A/B fragment row (M for A, N for B)
  const int g  = lane >> 4;       // 0..3
  const int fc = g * 8;           // K-chunk offset within fragment

  // ---- Q/K fragments straight from global (contiguous bf16x8 per lane) ----
  bf16x8 qf[4][2], kf[4][2];
#pragma unroll
  for (int mt = 0; mt < 4; mt++) {
    const int i = mt * 16 + fr;
    const bool ok = (i < NTOK);
    const u16* qrow = QK + (rowbase + (ok ? i : 0)) * (size_t)1024 + h * HD;
#pragma unroll
    for (int kt = 0; kt < 2; kt++) {
      bf16x8 qz = {}, kz = {};
      if (ok) {
        qz = *(const bf16x8*)&qrow[kt * 32 + fc];
        kz = *(const bf16x8*)&qrow[DIMV + kt * 32 + fc];
      }
      qf[mt][kt] = qz;
      kf[mt][kt] = kz;
    }
  }

  // ---- S = Q @ K^T  (rows i = queries, cols j = keys) ----
  f32x4 sa[4][4] = {};
#pragma unroll
  for (int kt = 0; kt < 2; kt++)
#pragma unroll
    for (int mt = 0; mt < 4; mt++)
#pragma unroll
      for (int nt = 0; nt < 4; nt++)
        sa[mt][nt] = __builtin_amdgcn_mfma_f32_16x16x32_bf16(
            qf[mt][kt], kf[nt][kt], sa[mt][nt], 0, 0, 0);

  // ---- V B-fragments (strided scalar loads) issued NOW so L2 latency hides
  //      under the softmax VALU work ----
  bf16x8 vb[2][4];
  const u16* vbase = V + rowbase * (size_t)DIMV + h * HD;
#pragma unroll
  for (int kt = 0; kt < 2; kt++)
#pragma unroll
    for (int nt = 0; nt < 4; nt++) {
      u16x8 tmp;
#pragma unroll
      for (int t = 0; t < 8; t++) {
        const int j = kt * 32 + fc + t;
        const int jr = (j < NTOK) ? j : (NTOK - 1);  // pad rows: P==0 there
        tmp[t] = vbase[(size_t)jr * DIMV + nt * 16 + fr];
      }
      vb[kt][nt] = __builtin_bit_cast(bf16x8, tmp);
    }

  // ---- scale + mask + wave-parallel softmax ----
  // C layout: S[i][j], i = mt*16 + g*4 + r, j = nt*16 + fr
#pragma unroll
  for (int mt = 0; mt < 4; mt++) {
#pragma unroll
    for (int r = 0; r < 4; r++) {
      const int i = mt * 16 + g * 4 + r;
      const int im = (i < NTOK) ? i : (NTOK - 1);
      float m = -1e30f;
#pragma unroll
      for (int nt = 0; nt < 4; nt++) {
        const int j = nt * 16 + fr;
        float v = sa[mt][nt][r] * 0.125f;  // SCALE = 64^-0.5 (exact pow2)
        v = (j < NTOK) ? (v + msk[im * NTOK + j]) : -1e30f;
        sa[mt][nt][r] = v;
        m = fmaxf(m, v);
      }
#pragma unroll
      for (int d = 1; d < 16; d <<= 1) m = fmaxf(m, __shfl_xor(m, d));
      float s = 0.f;
#pragma unroll
      for (int nt = 0; nt < 4; nt++) {
        const float p = __expf(sa[mt][nt][r] - m);
        sa[mt][nt][r] = p;
        s += p;
      }
#pragma unroll
      for (int d = 1; d < 16; d <<= 1) s += __shfl_xor(s, d);
      const float inv = 1.f / s;
#pragma unroll
      for (int nt = 0; nt < 4; nt++) {
        const int j = nt * 16 + fr;
        Pl[wv][(i * 64 + j) ^ ((i & 7) << 3)] = f2bf(sa[mt][nt][r] * inv);
      }
    }
  }
  __syncthreads();  // guarantees P writes visible before b128 reads

  // ---- out = P @ V ----
  f32x4 oacc[4][4] = {};
#pragma unroll
  for (int kt = 0; kt < 2; kt++) {
    bf16x8 pa[4];
#pragma unroll
    for (int mt = 0; mt < 4; mt++) {
      const int i = mt * 16 + fr;
      pa[mt] = *(const bf16x8*)&Pl[wv][(i * 64 + kt * 32 + fc) ^ ((i & 7) << 3)];
    }
#pragma unroll
    for (int mt = 0; mt < 4; mt++)
#pragma unroll
      for (int nt = 0; nt < 4; nt++)
        oacc[mt][nt] = __builtin_amdgcn_mfma_f32_16x16x32_bf16(
            pa[mt], vb[kt][nt], oacc[mt][nt], 0, 0, 0);
  }

  // ---- write Att rows i<49; C layout row = mt*16+g*4+r, col = nt*16+fr ----
#pragma unroll
  for (int mt = 0; mt < 4; mt++)
#pragma unroll
    for (int r = 0; r < 4; r++) {
      const int i = mt * 16 + g * 4 + r;
      if (i < NTOK) {
#pragma unroll
        for (int nt = 0; nt < 4; nt++)
          Att[(rowbase + i) * (size_t)DIMV + h * HD + nt * 16 + fr] =
              f2bf(oacc[mt][nt][r]);
      }
    }
}

extern "C" void kernel_launch(void* const* d_in, const int* in_sizes, int n_in,
                              void* d_out, int out_size, void* d_ws, size_t ws_size,
                              hipStream_t stream) {
  const float* x    = (const float*)d_in[0];
  const float* mask = (const float*)d_in[1];
  const float* Wq   = (const float*)d_in[2];
  const float* bq   = (const float*)d_in[3];
  const float* Wk   = (const float*)d_in[4];
  const float* bk   = (const float*)d_in[5];
  const float* Wv   = (const float*)d_in[6];
  const float* bv   = (const float*)d_in[7];
  const float* Wp   = (const float*)d_in[8];
  const float* bp   = (const float*)d_in[9];

  char* ws = (char*)d_ws;
  size_t off = 0;
  auto alloc = [&](size_t bytes) {
    char* p = ws + off;
    off += (bytes + 255) & ~(size_t)255;
    return p;
  };
  u16* Xb  = (u16*)alloc((size_t)MROWS * CIN * 2);    // 205.5 MB
  u16* QKb = (u16*)alloc((size_t)MROWS * 1024 * 2);   // 205.5 MB
  u16* Vb  = (u16*)alloc((size_t)MROWS * 512 * 2);    // 102.8 MB
  u16* W1T = (u16*)alloc(1024 * 1024 * 2);
  u16* WvT = (u16*)alloc(512 * 512 * 2);
  u16* WpT = (u16*)alloc(1024 * 512 * 2);
  float* bqk = (float*)alloc(1024 * 4);
  u16* Attb = Xb;  // alias: Xb is dead after the V GEMM
  if (off > ws_size) return;  // workspace too small -> fail visibly (zero output)

  // 1) x -> bf16
  {
    long n4 = (long)MROWS * CIN / 4;  // 25,690,112 = 256 * 100352
    convert_f32_bf16_kernel<<<dim3((unsigned)((n4 + 255) / 256)), 256, 0, stream>>>(
        (const float4*)x, (ushort4*)Xb, n4);
  }
  // 2) weight transposes (B^T layout, bf16) + fused bias
  transpose_f32_bf16_kernel<<<dim3(16, 32), 256, 0, stream>>>(Wq, 1024, 512, W1T, 1024);
  transpose_f32_bf16_kernel<<<dim3(16, 32), 256, 0, stream>>>(Wk, 1024, 512, W1T + (size_t)512 * 1024, 1024);
  transpose_f32_bf16_kernel<<<dim3(16, 16), 256, 0, stream>>>(Wv, 512, 512, WvT, 512);
  transpose_f32_bf16_kernel<<<dim3(32, 16), 256, 0, stream>>>(Wp, 512, 1024, WpT, 512);
  bias_concat_kernel<<<dim3(4), 256, 0, stream>>>(bq, bk, bqk);

  // 3) QK = Xb @ [Wq|Wk] + [bq|bk]   (M x 1024, bf16 out)
  gemm_bt_kernel<1><<<dim3(8, MROWS / 128), 256, 0, stream>>>(
      Xb, 1024, W1T, bqk, (void*)QKb, 1024, 1024);
  // 4) V = Xb[:, :512] @ Wv + bv     (M x 512, bf16 out)
  gemm_bt_kernel<1><<<dim3(4, MROWS / 128), 256, 0, stream>>>(
      Xb, 1024, WvT, bv, (void*)Vb, 512, 512);
  // 5) MFMA attention: 2 blocks/window, 1 wave per head
  attn_kernel<<<dim3(4096), 256, 0, stream>>>(QKb, Vb, mask, Attb);
  // 6) out = Att @ Wp + bp           (M x 1024, fp32 out)
  gemm_bt_kernel<0><<<dim3(8, MROWS / 128), 256, 0, stream>>>(
      Attb, 512, WpT, bp, d_out, 1024, 512);
}